// Round 2
// baseline (1113.251 us; speedup 1.0000x reference)
//
#include <hip/hip_runtime.h>
#include <hip/hip_fp16.h>

#define H 256
#define HETD 3
#define AH 128
#define BSEG 64
#define ROWS 32      // nodes per block (single-wave blocks)
#define LSTR 260     // fp32 stride of staged row: 1040 B (16B-aligned, bank shift 4/row)

typedef _Float16 half8 __attribute__((ext_vector_type(8)));
typedef __attribute__((ext_vector_type(4))) float f32x4;

__device__ __forceinline__ _Float16 f2h(float f) { return (_Float16)f; }

// ---------------------------------------------------------------------------
// Pack W1 [259][128] fp32 -> f16 MFMA B-fragments.
// Frag index ((t*8 + nt)*64 + lane), 8 f16/lane.
// B[k][n]: n = nt*16 + (lane&15), k = t*32 + (lane>>4)*8 + j, zero-pad k>=259.
// ---------------------------------------------------------------------------
__global__ void pack_w1_kernel(const float* __restrict__ W1,
                               unsigned short* __restrict__ W1p) {
    int idx = blockIdx.x * 256 + threadIdx.x;
    if (idx >= 9 * 8 * 64 * 8) return;
    int j    = idx & 7;
    int lane = (idx >> 3) & 63;
    int nt   = (idx >> 9) & 7;
    int t    = idx >> 12;
    int n = nt * 16 + (lane & 15);
    int k = t * 32 + ((lane >> 4) & 3) * 8 + j;
    float w = (k < (H + HETD)) ? W1[k * AH + n] : 0.f;
    __half hw = __float2half(w);
    W1p[idx] = __half_as_ushort(hw);
}

// ---------------------------------------------------------------------------
// Fused gate + weighted accumulate. One wave per block, 32 nodes per block.
// Phase 1: stage 32x256 fp32 x-tile to LDS (coalesced, x read from HBM ONCE).
// Phase 2: gate MLP via 16x16x32 f16 MFMA (M=32, N=128, K=288), A from LDS.
//          Epilogue tanh -> @W2 -> exp; p -> global + LDS; denom -> LDS sd.
// Phase 3: S[seg][:] += p_i * x_i from the LDS tile (register run-accumulate
//          over the sorted batch; atomics only at segment boundaries).
// ---------------------------------------------------------------------------
__global__ __launch_bounds__(64) void fused_kernel(
    const float* __restrict__ x, const float* __restrict__ het,
    const int* __restrict__ batch, const unsigned short* __restrict__ W1p,
    const float* __restrict__ b1, const float* __restrict__ W2,
    const float* __restrict__ b2, float* __restrict__ p,
    float* __restrict__ d, float* __restrict__ S, int n_nodes)
{
    __shared__ float sx[ROWS * LSTR];   // 33,280 B
    __shared__ float psh[ROWS];
    __shared__ int   sbatch[ROWS];
    __shared__ float sd[BSEG];

    const int lane = threadIdx.x;       // 0..63
    const int row  = lane & 15;
    const int quad = lane >> 4;
    const long long base = (long long)blockIdx.x * ROWS;

    sd[lane] = 0.f;
    if (lane < ROWS) {
        long long nd = base + lane;
        sbatch[lane] = batch[nd < n_nodes ? nd : (long long)(n_nodes - 1)];
    }

    // ---- Phase 1: stage x tile (ROWS x 256 fp32), 1 KB per row, coalesced --
#pragma unroll
    for (int c = 0; c < ROWS / 16; ++c) {
        float4 tmp[16];
#pragma unroll
        for (int j = 0; j < 16; ++j) {
            long long nd = base + c * 16 + j;
            if (nd >= n_nodes) nd = n_nodes - 1;
            tmp[j] = ((const float4*)(x + (size_t)nd * H))[lane];
        }
#pragma unroll
        for (int j = 0; j < 16; ++j)
            *(float4*)(sx + (c * 16 + j) * LSTR + lane * 4) = tmp[j];
    }

    // per-lane epilogue weights: n = nt*16 + row  (L1/L2 resident)
    float w2r[8], b1r[8];
#pragma unroll
    for (int nt = 0; nt < 8; ++nt) {
        w2r[nt] = W2[nt * 16 + row];
        b1r[nt] = b1[nt * 16 + row];
    }
    float b2v = b2[0];

    __syncthreads();

    // ---- Phase 2: gate MFMA, M=32 (2 mtiles) x N=128 (8 ntiles) x K=288 ----
    f32x4 acc[2][8] = {};
    const uint4* W1p4 = (const uint4*)W1p;
#pragma unroll
    for (int t = 0; t < 8; ++t) {
        half8 a[2];
#pragma unroll
        for (int m = 0; m < 2; ++m) {
            const float4* xr =
                (const float4*)(sx + (m * 16 + row) * LSTR + t * 32 + quad * 8);
            float4 lo = xr[0], hi = xr[1];
            half8 av;
            av[0] = f2h(lo.x); av[1] = f2h(lo.y);
            av[2] = f2h(lo.z); av[3] = f2h(lo.w);
            av[4] = f2h(hi.x); av[5] = f2h(hi.y);
            av[6] = f2h(hi.z); av[7] = f2h(hi.w);
            a[m] = av;
        }
#pragma unroll
        for (int nt = 0; nt < 8; ++nt) {
            union { uint4 u; half8 h; } cv;
            cv.u = W1p4[(t * 8 + nt) * 64 + lane];
#pragma unroll
            for (int m = 0; m < 2; ++m)
                acc[m][nt] = __builtin_amdgcn_mfma_f32_16x16x32_f16(
                    a[m], cv.h, acc[m][nt], 0, 0, 0);
        }
    }
    {   // het ktile (k = 256..258 + zero pad)
        half8 a[2];
#pragma unroll
        for (int m = 0; m < 2; ++m) {
            half8 av = {0, 0, 0, 0, 0, 0, 0, 0};
            if (quad == 0) {
                long long nd = base + m * 16 + row;
                if (nd >= n_nodes) nd = n_nodes - 1;
                const float* hr = het + (size_t)nd * HETD;
                av[0] = f2h(hr[0]); av[1] = f2h(hr[1]); av[2] = f2h(hr[2]);
            }
            a[m] = av;
        }
#pragma unroll
        for (int nt = 0; nt < 8; ++nt) {
            union { uint4 u; half8 h; } cv;
            cv.u = W1p4[(8 * 8 + nt) * 64 + lane];
#pragma unroll
            for (int m = 0; m < 2; ++m)
                acc[m][nt] = __builtin_amdgcn_mfma_f32_16x16x32_f16(
                    a[m], cv.h, acc[m][nt], 0, 0, 0);
        }
    }

    // ---- Epilogue: tanh -> @W2 -> exp.  C/D: n = nt*16+row,
    //      node_local = m*16 + quad*4 + r ----
#pragma unroll
    for (int m = 0; m < 2; ++m) {
#pragma unroll
        for (int r = 0; r < 4; ++r) {
            float partial = 0.f;
#pragma unroll
            for (int nt = 0; nt < 8; ++nt) {
                float h = acc[m][nt][r] + b1r[nt];
                float e2 = __expf(2.f * h);          // tanh = 1 - 2/(e^{2h}+1)
                partial += (1.f - 2.f / (e2 + 1.f)) * w2r[nt];
            }
            partial += __shfl_xor(partial, 1);
            partial += __shfl_xor(partial, 2);
            partial += __shfl_xor(partial, 4);
            partial += __shfl_xor(partial, 8);
            if (row == r) {
                int nl = m * 16 + quad * 4 + r;
                long long node = base + nl;
                float pe = 0.f;
                if (node < n_nodes) {
                    pe = __expf(partial + b2v);
                    p[node] = pe;
                    atomicAdd(&sd[sbatch[nl]], pe);
                }
                psh[nl] = pe;                        // 0 for tail rows
            }
        }
    }
    __syncthreads();

    // ---- Phase 3: S[seg] += p * x from LDS (run-accumulate, sorted batch) --
    {
        float ax = 0.f, ay = 0.f, az = 0.f, aw = 0.f;
        int cur = -1;
        for (int i = 0; i < ROWS; ++i) {
            int sg = sbatch[i];                      // wave-uniform
            float pi = psh[i];
            if (sg != cur) {
                if (cur >= 0) {
                    float* Sp = S + cur * H + lane * 4;
                    atomicAdd(Sp + 0, ax); atomicAdd(Sp + 1, ay);
                    atomicAdd(Sp + 2, az); atomicAdd(Sp + 3, aw);
                }
                cur = sg; ax = ay = az = aw = 0.f;
            }
            float4 xv = *(const float4*)(sx + i * LSTR + lane * 4);
            ax += pi * xv.x; ay += pi * xv.y;
            az += pi * xv.z; aw += pi * xv.w;
        }
        if (cur >= 0) {
            float* Sp = S + cur * H + lane * 4;
            atomicAdd(Sp + 0, ax); atomicAdd(Sp + 1, ay);
            atomicAdd(Sp + 2, az); atomicAdd(Sp + 3, aw);
        }
    }
    __syncthreads();
    {   // per-block denominators -> global (only 1-2 nonzero: batch sorted)
        float v = sd[lane];
        if (v != 0.f) atomicAdd(&d[lane], v);
    }
}

// ---------------------------------------------------------------------------
// attn_i = p_i / d[batch_i]
// ---------------------------------------------------------------------------
__global__ void attn_kernel(const float* __restrict__ p,
                            const int* __restrict__ batch,
                            const float* __restrict__ d,
                            float* __restrict__ attn, int n_nodes) {
    int i = blockIdx.x * 256 + threadIdx.x;
    if (i < n_nodes) attn[i] = p[i] / d[batch[i]];
}

// ---------------------------------------------------------------------------
// z[b] = (S[b]/d[b]) @ Wv + bv   (empty segment -> 0, matching segsum)
// ---------------------------------------------------------------------------
__global__ __launch_bounds__(256) void z_kernel(
    const float* __restrict__ S, const float* __restrict__ d,
    const float* __restrict__ Wv, const float* __restrict__ bv,
    float* __restrict__ z)
{
    __shared__ float sA[H];
    int b = blockIdx.x;
    int j = threadIdx.x;
    float dv = d[b];
    float inv = (dv != 0.f) ? 1.f / dv : 0.f;
    sA[j] = S[b * H + j] * inv;
    __syncthreads();
    float sum = (dv != 0.f) ? bv[j] : 0.f;
#pragma unroll 4
    for (int h = 0; h < H; ++h)
        sum += sA[h] * Wv[h * H + j];
    z[b * H + j] = sum;
}

extern "C" void kernel_launch(void* const* d_in, const int* in_sizes, int n_in,
                              void* d_out, int out_size, void* d_ws, size_t ws_size,
                              hipStream_t stream)
{
    const float* x   = (const float*)d_in[0];
    const float* het = (const float*)d_in[1];
    const int*   bat = (const int*)d_in[2];
    const float* W1  = (const float*)d_in[3];
    const float* b1  = (const float*)d_in[4];
    const float* W2  = (const float*)d_in[5];
    const float* b2  = (const float*)d_in[6];
    const float* Wv  = (const float*)d_in[7];
    const float* bv  = (const float*)d_in[8];
    int n = in_sizes[0] / H;  // 500000

    // ws layout: d[64] | S[64*256] | p[n] | W1p (f16 frags, 36864 shorts)
    float* wsf = (float*)d_ws;
    float* d_d = wsf;
    float* d_S = wsf + BSEG;
    float* d_p = wsf + BSEG + BSEG * H;
    unsigned short* d_W1p = (unsigned short*)(wsf + BSEG + BSEG * H + n);

    hipMemsetAsync(d_d, 0, (BSEG + BSEG * H) * sizeof(float), stream);
    pack_w1_kernel<<<(9 * 8 * 64 * 8 + 255) / 256, 256, 0, stream>>>(W1, d_W1p);

    int nblocks = (n + ROWS - 1) / ROWS;
    fused_kernel<<<nblocks, 64, 0, stream>>>(x, het, bat, d_W1p,
                                             b1, W2, b2, d_p, d_d, d_S, n);
    attn_kernel<<<(n + 255) / 256, 256, 0, stream>>>(d_p, bat, d_d,
                                                     (float*)d_out + BSEG * H, n);
    z_kernel<<<BSEG, 256, 0, stream>>>(d_S, d_d, Wv, bv, (float*)d_out);
}